// Round 4
// baseline (268.865 us; speedup 1.0000x reference)
//
#include <hip/hip_runtime.h>

typedef unsigned short u16;
typedef unsigned int u32;
typedef short bf16x8 __attribute__((ext_vector_type(8)));
typedef float f32x4 __attribute__((ext_vector_type(4)));

#define NAG 32
#define STATE 512
#define EMBED 64
#define TB 32   // samples per block

// d_ws bf16 layout (u16 element offsets).
// [0, 131072)      : WA  = concat(w1l1w, w2l1w, b1w, b2l1w) as [256][512] feature-major
// [131072, 262144) : WB  = w1l2w [2048][64]
// [262144, 266240) : WC  = w2l2w [64][64]
#define OFF_W1L1 0
#define OFF_W2L1 32768
#define OFF_B1W  65536
#define OFF_B2L1 98304
#define OFF_W1L2 131072
#define OFF_W2L2 262144
#define WS_TOTAL 266240

__device__ __forceinline__ float bf2f(u16 u) {
    u32 i = ((u32)u) << 16; float f;
    __builtin_memcpy(&f, &i, 4); return f;
}
__device__ __forceinline__ u16 f2bf(float f) {
    u32 i; __builtin_memcpy(&i, &f, 4);
    return (u16)((i + 0x8000u) >> 16);
}
__device__ __forceinline__ bf16x8 ld8(const u16* p) {
    return *reinterpret_cast<const bf16x8*>(p);
}
__device__ __forceinline__ bf16x8 cvt8(f32x4 a, f32x4 b) {
    bf16x8 r;
#pragma unroll
    for (int i = 0; i < 4; ++i) r[i]     = (short)f2bf(a[i]);
#pragma unroll
    for (int i = 0; i < 4; ++i) r[i + 4] = (short)f2bf(b[i]);
    return r;
}

__global__ __launch_bounds__(256) void cvt_weights(
    const float* __restrict__ w1l1w, const float* __restrict__ w2l1w,
    const float* __restrict__ b1w,   const float* __restrict__ b2l1w,
    const float* __restrict__ w1l2w, const float* __restrict__ w2l2w,
    u16* __restrict__ ws)
{
    int idx = blockIdx.x * 256 + threadIdx.x;
    const float* src; int off;
    if      (idx < OFF_W2L1)  { src = w1l1w; off = OFF_W1L1; }
    else if (idx < OFF_B1W)   { src = w2l1w; off = OFF_W2L1; }
    else if (idx < OFF_B2L1)  { src = b1w;   off = OFF_B1W;  }
    else if (idx < OFF_W1L2)  { src = b2l1w; off = OFF_B2L1; }
    else if (idx < OFF_W2L2)  { src = w1l2w; off = OFF_W1L2; }
    else if (idx < WS_TOTAL)  { src = w2l2w; off = OFF_W2L2; }
    else return;
    ws[idx] = f2bf(src[idx - off]);
}

__global__ __launch_bounds__(256, 4) void qmix_kernel(
    const float* __restrict__ qs,    const float* __restrict__ st,
    const u16*  __restrict__ wsb,
    const float* __restrict__ w1l1b, const float* __restrict__ w1l2b,
    const float* __restrict__ w2l1b, const float* __restrict__ w2l2b,
    const float* __restrict__ b1b,   const float* __restrict__ b2l1b,
    const float* __restrict__ b2l2w, const float* __restrict__ b2l2b,
    float* __restrict__ out)
{
    // Y columns: [0:64) h1(relu), [64:128) h2(relu), [128:192) b1v(linear), [192:256) hb(relu)
    __shared__ u16  y[TB][264];
    __shared__ u16  hid[TB][72];
    __shared__ float qsl[TB][33];
    __shared__ float qacc[TB][2];
    __shared__ float b2w[64];

    const int t    = threadIdx.x;
    const int wave = t >> 6, lane = t & 63;
    const int m = lane & 15, quad = lane >> 4;
    const int sbase = blockIdx.x * TB;

    // ---- stage qs + b2w ----
    if (t < 64) b2w[t] = b2l2w[t];
    for (int i = t; i < TB * NAG; i += 256) {
        int s = i >> 5, a = i & 31;
        qsl[s][a] = qs[(size_t)(sbase + s) * NAG + a];
    }

    // ---- Phase A: Y[32][256] = states @ Wcat^T (+bias, act) ----
    // wave -> 16 samples (shalf) x 128 features (fhalf). No pointer arrays:
    // WA is one contiguous [256][512] matrix; tile tt = rows fbase+tt*16..+16.
    const int shalf = wave >> 1, fhalf = wave & 1;
    const int s0 = shalf * 16;
    const int fbase = fhalf * 128;

    const float* ap = st + (size_t)(sbase + s0 + m) * STATE + quad * 8;
    const u16*   bb = wsb + (size_t)(fbase + m) * STATE + quad * 8;

    // bias pointers: wave-uniform ternary, no runtime-indexed array
    const float* bgA = fhalf ? b1b   : w1l1b;   // tiles 0..3
    const float* bgB = fhalf ? b2l1b : w2l1b;   // tiles 4..7
    float abias[8];
#pragma unroll
    for (int tt = 0; tt < 4; ++tt) abias[tt]     = bgA[tt * 16 + m];
#pragma unroll
    for (int tt = 0; tt < 4; ++tt) abias[tt + 4] = bgB[tt * 16 + m];

    f32x4 acc[8] = {};
#pragma unroll
    for (int ks = 0; ks < 16; ++ks) {
        const int ko = ks * 32;
        f32x4 a0 = *reinterpret_cast<const f32x4*>(ap + ko);
        f32x4 a1 = *reinterpret_cast<const f32x4*>(ap + ko + 4);
        bf16x8 bt[8];
#pragma unroll
        for (int tt = 0; tt < 8; ++tt)
            bt[tt] = ld8(bb + tt * (16 * STATE) + ko);
        bf16x8 af = cvt8(a0, a1);
#pragma unroll
        for (int tt = 0; tt < 8; ++tt)
            acc[tt] = __builtin_amdgcn_mfma_f32_16x16x32_bf16(af, bt[tt], acc[tt], 0, 0, 0);
    }
#pragma unroll
    for (int tt = 0; tt < 8; ++tt) {
        const bool isrelu = (fhalf == 0) || (tt >= 4);   // group 2 (b1v) is linear
        const int fcol = fbase + tt * 16 + m;
#pragma unroll
        for (int r = 0; r < 4; ++r) {
            float v = acc[tt][r] + abias[tt];
            if (isrelu) v = fmaxf(v, 0.f);
            y[s0 + quad * 4 + r][fcol] = f2bf(v);
        }
    }
    __syncthreads();

    // ---- Phase B: hidden = elu(sum_a qs[s,a]*|h1 @ W1l2[a]^T + b| + b1v) ----
    const int e0 = (wave & 1) * 32;
    bf16x8 haf0 = *reinterpret_cast<const bf16x8*>(&y[s0 + m][quad * 8]);
    bf16x8 haf1 = *reinterpret_cast<const bf16x8*>(&y[s0 + m][32 + quad * 8]);

    // single base pointer; agent a adds a*4096, tile adds 1024 (u16 units)
    const u16* wb0 = wsb + OFF_W1L2 + (size_t)(e0 + m) * EMBED + quad * 8;
    const float* bb0 = w1l2b + e0 + m;

    f32x4 hacc0 = {}, hacc1 = {};
#pragma unroll
    for (int a = 0; a < NAG; ++a) {
        bf16x8 b00 = ld8(wb0 + a * 4096);
        bf16x8 b01 = ld8(wb0 + a * 4096 + 32);
        bf16x8 b10 = ld8(wb0 + a * 4096 + 1024);
        bf16x8 b11 = ld8(wb0 + a * 4096 + 1024 + 32);
        float bias0 = bb0[a * EMBED];
        float bias1 = bb0[a * EMBED + 16];
        float qv[4];
#pragma unroll
        for (int r = 0; r < 4; ++r) qv[r] = qsl[s0 + quad * 4 + r][a];

        f32x4 p0 = {}, p1 = {};
        p0 = __builtin_amdgcn_mfma_f32_16x16x32_bf16(haf0, b00, p0, 0, 0, 0);
        p0 = __builtin_amdgcn_mfma_f32_16x16x32_bf16(haf1, b01, p0, 0, 0, 0);
        p1 = __builtin_amdgcn_mfma_f32_16x16x32_bf16(haf0, b10, p1, 0, 0, 0);
        p1 = __builtin_amdgcn_mfma_f32_16x16x32_bf16(haf1, b11, p1, 0, 0, 0);
#pragma unroll
        for (int r = 0; r < 4; ++r) {
            hacc0[r] += qv[r] * fabsf(p0[r] + bias0);
            hacc1[r] += qv[r] * fabsf(p1[r] + bias1);
        }
    }
#pragma unroll
    for (int r = 0; r < 4; ++r) {
        int s = s0 + quad * 4 + r;
        float v0 = hacc0[r] + bf2f(y[s][128 + e0 + m]);
        v0 = (v0 > 0.f) ? v0 : (__expf(v0) - 1.f);
        hid[s][e0 + m] = f2bf(v0);
        float v1 = hacc1[r] + bf2f(y[s][128 + e0 + 16 + m]);
        v1 = (v1 > 0.f) ? v1 : (__expf(v1) - 1.f);
        hid[s][e0 + 16 + m] = f2bf(v1);
    }
    __syncthreads();

    // ---- Phase C: w2 = |h2 @ W2l2^T + b|; partial q = sum_e hidden*w2 ----
    bf16x8 h2f0 = *reinterpret_cast<const bf16x8*>(&y[s0 + m][64 + quad * 8]);
    bf16x8 h2f1 = *reinterpret_cast<const bf16x8*>(&y[s0 + m][64 + 32 + quad * 8]);

    const u16* wc0 = wsb + OFF_W2L2 + (size_t)((wave & 1) * 32 + m) * EMBED + quad * 8;
    f32x4 qp = {};
#pragma unroll
    for (int tp = 0; tp < 2; ++tp) {
        const int etile = (wave & 1) * 2 + tp;
        bf16x8 b0 = ld8(wc0 + tp * 1024);
        bf16x8 b1 = ld8(wc0 + tp * 1024 + 32);
        f32x4 p = {};
        p = __builtin_amdgcn_mfma_f32_16x16x32_bf16(h2f0, b0, p, 0, 0, 0);
        p = __builtin_amdgcn_mfma_f32_16x16x32_bf16(h2f1, b1, p, 0, 0, 0);
        float bias = w2l2b[etile * 16 + m];
#pragma unroll
        for (int r = 0; r < 4; ++r) {
            float w2v = fabsf(p[r] + bias);
            float hv = bf2f(hid[s0 + quad * 4 + r][etile * 16 + m]);
            qp[r] += hv * w2v;
        }
    }
#pragma unroll
    for (int off = 1; off < 16; off <<= 1) {
#pragma unroll
        for (int r = 0; r < 4; ++r) qp[r] += __shfl_xor(qp[r], off, 64);
    }
    if (m == 0) {
#pragma unroll
        for (int r = 0; r < 4; ++r) qacc[s0 + quad * 4 + r][wave & 1] = qp[r];
    }
    __syncthreads();

    // ---- Phase D: b2 + final sum (LDS-only) ----
    if (t < TB) {
        int s = t;
        float q = qacc[s][0] + qacc[s][1] + b2l2b[0];
        float acc2 = 0.f;
#pragma unroll
        for (int kk = 0; kk < 8; ++kk) {
            bf16x8 hv = *reinterpret_cast<const bf16x8*>(&y[s][192 + kk * 8]);
#pragma unroll
            for (int j = 0; j < 8; ++j)
                acc2 += bf2f((u16)hv[j]) * b2w[kk * 8 + j];
        }
        out[sbase + s] = q + acc2;
    }
}

extern "C" void kernel_launch(void* const* d_in, const int* in_sizes, int n_in,
                              void* d_out, int out_size, void* d_ws, size_t ws_size,
                              hipStream_t stream)
{
    const float* qs    = (const float*)d_in[0];
    const float* st    = (const float*)d_in[1];
    const float* w1l1w = (const float*)d_in[2];
    const float* w1l1b = (const float*)d_in[3];
    const float* w1l2w = (const float*)d_in[4];
    const float* w1l2b = (const float*)d_in[5];
    const float* w2l1w = (const float*)d_in[6];
    const float* w2l1b = (const float*)d_in[7];
    const float* w2l2w = (const float*)d_in[8];
    const float* w2l2b = (const float*)d_in[9];
    const float* b1w   = (const float*)d_in[10];
    const float* b1b   = (const float*)d_in[11];
    const float* b2l1w = (const float*)d_in[12];
    const float* b2l1b = (const float*)d_in[13];
    const float* b2l2w = (const float*)d_in[14];
    const float* b2l2b = (const float*)d_in[15];

    u16* wsb = (u16*)d_ws;

    cvt_weights<<<(WS_TOTAL + 255) / 256, 256, 0, stream>>>(
        w1l1w, w2l1w, b1w, b2l1w, w1l2w, w2l2w, wsb);

    int B = in_sizes[0] / NAG;        // 32768
    int grid = B / TB;                // 1024
    qmix_kernel<<<grid, 256, 0, stream>>>(
        qs, st, wsb,
        w1l1b, w1l2b, w2l1b, w2l2b, b1b, b2l1b, b2l2w, b2l2b,
        (float*)d_out);
}

// Round 5
// 237.905 us; speedup vs baseline: 1.1301x; 1.1301x over previous
//
#include <hip/hip_runtime.h>

typedef unsigned short u16;
typedef unsigned int u32;
typedef short bf16x8 __attribute__((ext_vector_type(8)));
typedef float f32x4 __attribute__((ext_vector_type(4)));

#define NAG 32
#define STATE 512
#define EMBED 64
#define TB 32   // samples per block

// d_ws bf16 layout (u16 element offsets).
// [0, 131072)      : WA  = concat(w1l1w, w2l1w, b1w, b2l1w) as [256][512] feature-major
// [131072, 262144) : WB  = w1l2w [2048][64]
// [262144, 266240) : WC  = w2l2w [64][64]
#define OFF_W1L1 0
#define OFF_W2L1 32768
#define OFF_B1W  65536
#define OFF_B2L1 98304
#define OFF_W1L2 131072
#define OFF_W2L2 262144
#define WS_TOTAL 266240

__device__ __forceinline__ float bf2f(u16 u) {
    u32 i = ((u32)u) << 16; float f;
    __builtin_memcpy(&f, &i, 4); return f;
}
__device__ __forceinline__ u16 f2bf(float f) {
    u32 i; __builtin_memcpy(&i, &f, 4);
    return (u16)((i + 0x8000u) >> 16);
}
__device__ __forceinline__ bf16x8 ld8(const u16* p) {
    return *reinterpret_cast<const bf16x8*>(p);
}
__device__ __forceinline__ bf16x8 cvt8(f32x4 a, f32x4 b) {
    bf16x8 r;
#pragma unroll
    for (int i = 0; i < 4; ++i) r[i]     = (short)f2bf(a[i]);
#pragma unroll
    for (int i = 0; i < 4; ++i) r[i + 4] = (short)f2bf(b[i]);
    return r;
}

__global__ __launch_bounds__(256) void cvt_weights(
    const float* __restrict__ w1l1w, const float* __restrict__ w2l1w,
    const float* __restrict__ b1w,   const float* __restrict__ b2l1w,
    const float* __restrict__ w1l2w, const float* __restrict__ w2l2w,
    u16* __restrict__ ws)
{
    int idx = blockIdx.x * 256 + threadIdx.x;
    const float* src; int off;
    if      (idx < OFF_W2L1)  { src = w1l1w; off = OFF_W1L1; }
    else if (idx < OFF_B1W)   { src = w2l1w; off = OFF_W2L1; }
    else if (idx < OFF_B2L1)  { src = b1w;   off = OFF_B1W;  }
    else if (idx < OFF_W1L2)  { src = b2l1w; off = OFF_B2L1; }
    else if (idx < OFF_W2L2)  { src = w1l2w; off = OFF_W1L2; }
    else if (idx < WS_TOTAL)  { src = w2l2w; off = OFF_W2L2; }
    else return;
    ws[idx] = f2bf(src[idx - off]);
}

__global__ __launch_bounds__(256, 2) void qmix_kernel(
    const float* __restrict__ qs,    const float* __restrict__ st,
    const u16*  __restrict__ wsb,
    const float* __restrict__ w1l1b, const float* __restrict__ w1l2b,
    const float* __restrict__ w2l1b, const float* __restrict__ w2l2b,
    const float* __restrict__ b1b,   const float* __restrict__ b2l1b,
    const float* __restrict__ b2l2w, const float* __restrict__ b2l2b,
    float* __restrict__ out)
{
    __shared__ u16  stl[TB][520];   // states bf16, +8 pad (perfect-spread b128 reads)
    __shared__ u16  y[TB][264];     // [0:64) h1, [64:128) h2, [128:192) b1v, [192:256) hb
    __shared__ u16  hid[TB][72];
    __shared__ float qsl[TB][33];
    __shared__ float w1b[2048];     // w1l2b staged f32
    __shared__ float qacc[TB][2];
    __shared__ float b2w[64];

    const int t    = threadIdx.x;
    const int wave = t >> 6, lane = t & 63;
    const int m = lane & 15, quad = lane >> 4;
    const int sbase = blockIdx.x * TB;

    // ---- stage qs (f32), b2w, w1l2b ----
    if (t < 64) b2w[t] = b2l2w[t];
    {
        int s = t >> 3, a8 = (t & 7) * 4;
        f32x4 qv = *reinterpret_cast<const f32x4*>(qs + (size_t)(sbase + s) * NAG + a8);
#pragma unroll
        for (int j = 0; j < 4; ++j) qsl[s][a8 + j] = qv[j];
    }
    {
        f32x4 a0 = *reinterpret_cast<const f32x4*>(w1l2b + t * 8);
        f32x4 a1 = *reinterpret_cast<const f32x4*>(w1l2b + t * 8 + 4);
        *reinterpret_cast<f32x4*>(&w1b[t * 8])     = a0;
        *reinterpret_cast<f32x4*>(&w1b[t * 8 + 4]) = a1;
    }

    // ---- stage states -> LDS bf16: wave w copies rows w, w+4, ..., w+28 ----
    // Each iter: one full 2KB state row per wave (64 lanes x 32B, perfectly coalesced).
#pragma unroll 2
    for (int i = 0; i < 8; ++i) {
        const int row = wave + i * 4;
        const float* src = st + (size_t)(sbase + row) * STATE + lane * 8;
        f32x4 a0 = *reinterpret_cast<const f32x4*>(src);
        f32x4 a1 = *reinterpret_cast<const f32x4*>(src + 4);
        *reinterpret_cast<bf16x8*>(&stl[row][lane * 8]) = cvt8(a0, a1);
    }
    __syncthreads();

    // ---- Phase A: Y[32][256] = states @ WA^T (+bias, act), A-frags from LDS ----
    const int shalf = wave >> 1, fhalf = wave & 1;
    const int s0 = shalf * 16;
    const int fbase = fhalf * 128;

    const u16* bb = wsb + (size_t)(fbase + m) * STATE + quad * 8;
    const float* bgA = fhalf ? b1b   : w1l1b;   // tiles 0..3
    const float* bgB = fhalf ? b2l1b : w2l1b;   // tiles 4..7
    float abias[8];
#pragma unroll
    for (int tt = 0; tt < 4; ++tt) abias[tt]     = bgA[tt * 16 + m];
#pragma unroll
    for (int tt = 0; tt < 4; ++tt) abias[tt + 4] = bgB[tt * 16 + m];

    f32x4 acc[8] = {};
#pragma unroll 2
    for (int ks = 0; ks < 16; ++ks) {
        const int ko = ks * 32;
        bf16x8 bt[8];
#pragma unroll
        for (int tt = 0; tt < 8; ++tt)
            bt[tt] = ld8(bb + tt * (16 * STATE) + ko);
        bf16x8 af = ld8(&stl[s0 + m][ko + quad * 8]);
#pragma unroll
        for (int tt = 0; tt < 8; ++tt)
            acc[tt] = __builtin_amdgcn_mfma_f32_16x16x32_bf16(af, bt[tt], acc[tt], 0, 0, 0);
    }
#pragma unroll
    for (int tt = 0; tt < 8; ++tt) {
        const bool isrelu = (fhalf == 0) || (tt >= 4);   // b1v tiles are linear
        const int fcol = fbase + tt * 16 + m;
#pragma unroll
        for (int r = 0; r < 4; ++r) {
            float v = acc[tt][r] + abias[tt];
            if (isrelu) v = fmaxf(v, 0.f);
            y[s0 + quad * 4 + r][fcol] = f2bf(v);
        }
    }
    __syncthreads();

    // ---- Phase B: hidden = elu(sum_a qs[s,a]*|h1 @ W1l2[a]^T + b| + b1v) ----
    const int e0 = (wave & 1) * 32;
    bf16x8 haf0 = *reinterpret_cast<const bf16x8*>(&y[s0 + m][quad * 8]);
    bf16x8 haf1 = *reinterpret_cast<const bf16x8*>(&y[s0 + m][32 + quad * 8]);

    const u16* wb0 = wsb + OFF_W1L2 + (size_t)(e0 + m) * EMBED + quad * 8;

    f32x4 hacc0 = {}, hacc1 = {};
#pragma unroll 4
    for (int a = 0; a < NAG; ++a) {
        bf16x8 b00 = ld8(wb0 + a * 4096);
        bf16x8 b01 = ld8(wb0 + a * 4096 + 32);
        bf16x8 b10 = ld8(wb0 + a * 4096 + 1024);
        bf16x8 b11 = ld8(wb0 + a * 4096 + 1024 + 32);
        float bias0 = w1b[a * EMBED + e0 + m];
        float bias1 = w1b[a * EMBED + e0 + 16 + m];
        float qv[4];
#pragma unroll
        for (int r = 0; r < 4; ++r) qv[r] = qsl[s0 + quad * 4 + r][a];

        f32x4 p0 = {}, p1 = {};
        p0 = __builtin_amdgcn_mfma_f32_16x16x32_bf16(haf0, b00, p0, 0, 0, 0);
        p0 = __builtin_amdgcn_mfma_f32_16x16x32_bf16(haf1, b01, p0, 0, 0, 0);
        p1 = __builtin_amdgcn_mfma_f32_16x16x32_bf16(haf0, b10, p1, 0, 0, 0);
        p1 = __builtin_amdgcn_mfma_f32_16x16x32_bf16(haf1, b11, p1, 0, 0, 0);
#pragma unroll
        for (int r = 0; r < 4; ++r) {
            hacc0[r] += qv[r] * fabsf(p0[r] + bias0);
            hacc1[r] += qv[r] * fabsf(p1[r] + bias1);
        }
    }
#pragma unroll
    for (int r = 0; r < 4; ++r) {
        int s = s0 + quad * 4 + r;
        float v0 = hacc0[r] + bf2f(y[s][128 + e0 + m]);
        v0 = (v0 > 0.f) ? v0 : (__expf(v0) - 1.f);
        hid[s][e0 + m] = f2bf(v0);
        float v1 = hacc1[r] + bf2f(y[s][128 + e0 + 16 + m]);
        v1 = (v1 > 0.f) ? v1 : (__expf(v1) - 1.f);
        hid[s][e0 + 16 + m] = f2bf(v1);
    }
    __syncthreads();

    // ---- Phase C: w2 = |h2 @ W2l2^T + b|; partial q = sum_e hidden*w2 ----
    bf16x8 h2f0 = *reinterpret_cast<const bf16x8*>(&y[s0 + m][64 + quad * 8]);
    bf16x8 h2f1 = *reinterpret_cast<const bf16x8*>(&y[s0 + m][64 + 32 + quad * 8]);

    const u16* wc0 = wsb + OFF_W2L2 + (size_t)((wave & 1) * 32 + m) * EMBED + quad * 8;
    f32x4 qp = {};
#pragma unroll
    for (int tp = 0; tp < 2; ++tp) {
        const int etile = (wave & 1) * 2 + tp;
        bf16x8 b0 = ld8(wc0 + tp * 1024);
        bf16x8 b1 = ld8(wc0 + tp * 1024 + 32);
        f32x4 p = {};
        p = __builtin_amdgcn_mfma_f32_16x16x32_bf16(h2f0, b0, p, 0, 0, 0);
        p = __builtin_amdgcn_mfma_f32_16x16x32_bf16(h2f1, b1, p, 0, 0, 0);
        float bias = w2l2b[etile * 16 + m];
#pragma unroll
        for (int r = 0; r < 4; ++r) {
            float w2v = fabsf(p[r] + bias);
            float hv = bf2f(hid[s0 + quad * 4 + r][etile * 16 + m]);
            qp[r] += hv * w2v;
        }
    }
#pragma unroll
    for (int off = 1; off < 16; off <<= 1) {
#pragma unroll
        for (int r = 0; r < 4; ++r) qp[r] += __shfl_xor(qp[r], off, 64);
    }
    if (m == 0) {
#pragma unroll
        for (int r = 0; r < 4; ++r) qacc[s0 + quad * 4 + r][wave & 1] = qp[r];
    }
    __syncthreads();

    // ---- Phase D: b2 + final sum (LDS-only) ----
    if (t < TB) {
        int s = t;
        float q = qacc[s][0] + qacc[s][1] + b2l2b[0];
        float acc2 = 0.f;
#pragma unroll
        for (int kk = 0; kk < 8; ++kk) {
            bf16x8 hv = *reinterpret_cast<const bf16x8*>(&y[s][192 + kk * 8]);
#pragma unroll
            for (int j = 0; j < 8; ++j)
                acc2 += bf2f((u16)hv[j]) * b2w[kk * 8 + j];
        }
        out[sbase + s] = q + acc2;
    }
}

extern "C" void kernel_launch(void* const* d_in, const int* in_sizes, int n_in,
                              void* d_out, int out_size, void* d_ws, size_t ws_size,
                              hipStream_t stream)
{
    const float* qs    = (const float*)d_in[0];
    const float* st    = (const float*)d_in[1];
    const float* w1l1w = (const float*)d_in[2];
    const float* w1l1b = (const float*)d_in[3];
    const float* w1l2w = (const float*)d_in[4];
    const float* w1l2b = (const float*)d_in[5];
    const float* w2l1w = (const float*)d_in[6];
    const float* w2l1b = (const float*)d_in[7];
    const float* w2l2w = (const float*)d_in[8];
    const float* w2l2b = (const float*)d_in[9];
    const float* b1w   = (const float*)d_in[10];
    const float* b1b   = (const float*)d_in[11];
    const float* b2l1w = (const float*)d_in[12];
    const float* b2l1b = (const float*)d_in[13];
    const float* b2l2w = (const float*)d_in[14];
    const float* b2l2b = (const float*)d_in[15];

    u16* wsb = (u16*)d_ws;

    cvt_weights<<<(WS_TOTAL + 255) / 256, 256, 0, stream>>>(
        w1l1w, w2l1w, b1w, b2l1w, w1l2w, w2l2w, wsb);

    int B = in_sizes[0] / NAG;        // 32768
    int grid = B / TB;                // 1024
    qmix_kernel<<<grid, 256, 0, stream>>>(
        qs, st, wsb,
        w1l1b, w1l2b, w2l1b, w2l2b, b1b, b2l1b, b2l2w, b2l2b,
        (float*)d_out);
}

// Round 6
// 156.305 us; speedup vs baseline: 1.7201x; 1.5221x over previous
//
#include <hip/hip_runtime.h>

typedef unsigned short u16;
typedef unsigned int u32;
typedef short bf16x8 __attribute__((ext_vector_type(8)));
typedef float f32x4 __attribute__((ext_vector_type(4)));

#define NAG 32
#define STATE 512
#define EMBED 64
#define TB 32   // samples per block

// d_ws bf16 layout (u16 element offsets).
// [0, 131072)      : WA  = concat(w1l1w, w2l1w, b1w, b2l1w) as [256][512] feature-major
// [131072, 262144) : WB  = w1l2w [2048][64]
// [262144, 266240) : WC  = w2l2w [64][64]
#define OFF_W1L1 0
#define OFF_W2L1 32768
#define OFF_B1W  65536
#define OFF_B2L1 98304
#define OFF_W1L2 131072
#define OFF_W2L2 262144
#define WS_TOTAL 266240

__device__ __forceinline__ float bf2f(u16 u) {
    u32 i = ((u32)u) << 16; float f;
    __builtin_memcpy(&f, &i, 4); return f;
}
__device__ __forceinline__ u16 f2bf(float f) {
    u32 i; __builtin_memcpy(&i, &f, 4);
    return (u16)((i + 0x8000u) >> 16);
}
__device__ __forceinline__ bf16x8 ld8(const u16* p) {
    return *reinterpret_cast<const bf16x8*>(p);
}
__device__ __forceinline__ bf16x8 cvt8(f32x4 a, f32x4 b) {
    bf16x8 r;
#pragma unroll
    for (int i = 0; i < 4; ++i) r[i]     = (short)f2bf(a[i]);
#pragma unroll
    for (int i = 0; i < 4; ++i) r[i + 4] = (short)f2bf(b[i]);
    return r;
}
// async global->LDS DMA, 16B per lane. LDS dest is wave-uniform base + lane*16;
// we pass per-lane base+lane*16 which matches HW semantics exactly.
__device__ __forceinline__ void dma16(const void* g, void* l) {
    __builtin_amdgcn_global_load_lds(
        (const __attribute__((address_space(1))) u32*)g,
        (__attribute__((address_space(3))) u32*)l, 16, 0, 0);
}

__global__ __launch_bounds__(256) void cvt_weights(
    const float* __restrict__ w1l1w, const float* __restrict__ w2l1w,
    const float* __restrict__ b1w,   const float* __restrict__ b2l1w,
    const float* __restrict__ w1l2w, const float* __restrict__ w2l2w,
    u16* __restrict__ ws)
{
    int idx = blockIdx.x * 256 + threadIdx.x;
    const float* src; int off;
    if      (idx < OFF_W2L1)  { src = w1l1w; off = OFF_W1L1; }
    else if (idx < OFF_B1W)   { src = w2l1w; off = OFF_W2L1; }
    else if (idx < OFF_B2L1)  { src = b1w;   off = OFF_B1W;  }
    else if (idx < OFF_W1L2)  { src = b2l1w; off = OFF_B2L1; }
    else if (idx < OFF_W2L2)  { src = w1l2w; off = OFF_W1L2; }
    else if (idx < WS_TOTAL)  { src = w2l2w; off = OFF_W2L2; }
    else return;
    ws[idx] = f2bf(src[idx - off]);
}

__global__ __launch_bounds__(256, 2) void qmix_kernel(
    const float* __restrict__ qs,    const float* __restrict__ st,
    const u16*  __restrict__ wsb,
    const float* __restrict__ w1l1b, const float* __restrict__ w1l2b,
    const float* __restrict__ w2l1b, const float* __restrict__ w2l2b,
    const float* __restrict__ b1b,   const float* __restrict__ b2l1b,
    const float* __restrict__ b2l2w, const float* __restrict__ b2l2b,
    float* __restrict__ out)
{
    __shared__ u16   wbuf[256 * 64];   // 32 KB weight slice (chunk-XOR-swizzled)
    __shared__ float sbuf[TB * 64];    // 8 KB state k-slice f32 (chunk-XOR-swizzled)
    __shared__ u16   y[TB][264];       // [0:64) h1, [64:128) h2, [128:192) b1v, [192:256) hb
    __shared__ u16   hid[TB][72];
    __shared__ float qsl[TB][33];
    __shared__ float w1b[2048];
    __shared__ float qacc[TB][2];
    __shared__ float b2w[64];

    const int t    = threadIdx.x;
    const int wave = t >> 6, lane = t & 63;
    const int m = lane & 15, quad = lane >> 4;
    const int sbase = blockIdx.x * TB;

    // ---- stage qs (f32), b2w, w1l2b (per-lane, once) ----
    if (t < 64) b2w[t] = b2l2w[t];
    {
        int s = t >> 3, a8 = (t & 7) * 4;
        f32x4 qv = *reinterpret_cast<const f32x4*>(qs + (size_t)(sbase + s) * NAG + a8);
#pragma unroll
        for (int j = 0; j < 4; ++j) qsl[s][a8 + j] = qv[j];
    }
    {
        f32x4 a0 = *reinterpret_cast<const f32x4*>(w1l2b + t * 8);
        f32x4 a1 = *reinterpret_cast<const f32x4*>(w1l2b + t * 8 + 4);
        *reinterpret_cast<f32x4*>(&w1b[t * 8])     = a0;
        *reinterpret_cast<f32x4*>(&w1b[t * 8 + 4]) = a1;
    }

    // ---- Phase A: Y[32][256] = states @ WA^T (+bias, act), K-sliced DMA ----
    const int shalf = wave >> 1, fhalf = wave & 1;
    const int s0 = shalf * 16;
    const int fbase = fhalf * 128;

    const float* bgA = fhalf ? b1b   : w1l1b;   // tiles 0..3
    const float* bgB = fhalf ? b2l1b : w2l1b;   // tiles 4..7
    float abias[8];
#pragma unroll
    for (int tt = 0; tt < 4; ++tt) abias[tt]     = bgA[tt * 16 + m];
#pragma unroll
    for (int tt = 0; tt < 4; ++tt) abias[tt + 4] = bgB[tt * 16 + m];

    f32x4 acc[8] = {};
    for (int ksl = 0; ksl < 8; ++ksl) {
        __syncthreads();   // previous slice fully consumed
        // stage WA k-slice [256 rows][64 u16]: wave stages rows wave*64..+63
        {
            const int rsub = lane >> 3, c = lane & 7;
#pragma unroll
            for (int j = 0; j < 8; ++j) {
                const int row = wave * 64 + j * 8 + rsub;
                const int sc  = c ^ (row & 7);
                dma16(wsb + (size_t)row * STATE + ksl * 64 + sc * 8,
                      &wbuf[(wave * 64 + j * 8) * 64 + lane * 8]);
            }
        }
        // stage states k-slice [32 rows][64 f32]: wave stages rows wave*8..+7
        {
            const int rs = lane >> 4, cs = lane & 15;
#pragma unroll
            for (int j = 0; j < 2; ++j) {
                const int row = wave * 8 + j * 4 + rs;
                const int sc  = cs ^ (row & 15);
                dma16(st + (size_t)(sbase + row) * STATE + ksl * 64 + sc * 4,
                      &sbuf[(wave * 8 + j * 4) * 64 + lane * 4]);
            }
        }
        __builtin_amdgcn_s_waitcnt(0);
        __syncthreads();
        // consume: 2 k-steps of 32
#pragma unroll
        for (int ks = 0; ks < 2; ++ks) {
            const int arow = s0 + m;
            const int gc = ks * 8 + quad * 2;
            f32x4 a0 = *reinterpret_cast<const f32x4*>(&sbuf[arow * 64 + ((gc    ) ^ (arow & 15)) * 4]);
            f32x4 a1 = *reinterpret_cast<const f32x4*>(&sbuf[arow * 64 + ((gc + 1) ^ (arow & 15)) * 4]);
            bf16x8 af = cvt8(a0, a1);
#pragma unroll
            for (int tt = 0; tt < 8; ++tt) {
                const int brow = fbase + tt * 16 + m;
                bf16x8 bf = ld8(&wbuf[brow * 64 + ((ks * 4 + quad) ^ (brow & 7)) * 8]);
                acc[tt] = __builtin_amdgcn_mfma_f32_16x16x32_bf16(af, bf, acc[tt], 0, 0, 0);
            }
        }
    }
#pragma unroll
    for (int tt = 0; tt < 8; ++tt) {
        const bool isrelu = (fhalf == 0) || (tt >= 4);   // b1v tiles are linear
        const int fcol = fbase + tt * 16 + m;
#pragma unroll
        for (int r = 0; r < 4; ++r) {
            float v = acc[tt][r] + abias[tt];
            if (isrelu) v = fmaxf(v, 0.f);
            y[s0 + quad * 4 + r][fcol] = f2bf(v);
        }
    }
    __syncthreads();

    // ---- Phase B: hidden = elu(sum_a qs[s,a]*|h1 @ W1l2[a]^T + b| + b1v) ----
    const int e0 = (wave & 1) * 32;
    bf16x8 haf0 = *reinterpret_cast<const bf16x8*>(&y[s0 + m][quad * 8]);
    bf16x8 haf1 = *reinterpret_cast<const bf16x8*>(&y[s0 + m][32 + quad * 8]);

    f32x4 hacc[2] = {};
    for (int bs = 0; bs < 8; ++bs) {
        // stage WB slice: rows bs*256 .. bs*256+255 (agents 4bs..4bs+3)
        {
            const int rsub = lane >> 3, c = lane & 7;
#pragma unroll
            for (int j = 0; j < 8; ++j) {
                const int row = wave * 64 + j * 8 + rsub;   // local row in slice
                const int sc  = c ^ (row & 7);
                dma16(wsb + OFF_W1L2 + ((size_t)bs * 256 + row) * EMBED + sc * 8,
                      &wbuf[(wave * 64 + j * 8) * 64 + lane * 8]);
            }
        }
        __builtin_amdgcn_s_waitcnt(0);
        __syncthreads();
#pragma unroll
        for (int aloc = 0; aloc < 4; ++aloc) {
            const int a = bs * 4 + aloc;
            float qv[4];
#pragma unroll
            for (int r = 0; r < 4; ++r) qv[r] = qsl[s0 + quad * 4 + r][a];
#pragma unroll
            for (int tp = 0; tp < 2; ++tp) {
                const int row = aloc * 64 + e0 + tp * 16 + m;   // local row in slice
                bf16x8 b0 = ld8(&wbuf[row * 64 + ((    quad) ^ (row & 7)) * 8]);
                bf16x8 b1 = ld8(&wbuf[row * 64 + ((4 + quad) ^ (row & 7)) * 8]);
                f32x4 p = {};
                p = __builtin_amdgcn_mfma_f32_16x16x32_bf16(haf0, b0, p, 0, 0, 0);
                p = __builtin_amdgcn_mfma_f32_16x16x32_bf16(haf1, b1, p, 0, 0, 0);
                float bias = w1b[a * EMBED + e0 + tp * 16 + m];
#pragma unroll
                for (int r = 0; r < 4; ++r)
                    hacc[tp][r] += qv[r] * fabsf(p[r] + bias);
            }
        }
        __syncthreads();   // slice consumed before restage
    }
#pragma unroll
    for (int tp = 0; tp < 2; ++tp) {
#pragma unroll
        for (int r = 0; r < 4; ++r) {
            int s = s0 + quad * 4 + r, e = e0 + tp * 16 + m;
            float v = hacc[tp][r] + bf2f(y[s][128 + e]);
            v = (v > 0.f) ? v : (__expf(v) - 1.f);
            hid[s][e] = f2bf(v);
        }
    }
    __syncthreads();

    // ---- Phase C: w2 = |h2 @ W2l2^T + b|; partial q = sum_e hidden*w2 ----
    bf16x8 h2f0 = *reinterpret_cast<const bf16x8*>(&y[s0 + m][64 + quad * 8]);
    bf16x8 h2f1 = *reinterpret_cast<const bf16x8*>(&y[s0 + m][64 + 32 + quad * 8]);

    const u16* wc0 = wsb + OFF_W2L2 + (size_t)((wave & 1) * 32 + m) * EMBED + quad * 8;
    f32x4 qp = {};
#pragma unroll
    for (int tp = 0; tp < 2; ++tp) {
        const int etile = (wave & 1) * 2 + tp;
        bf16x8 b0 = ld8(wc0 + tp * 1024);
        bf16x8 b1 = ld8(wc0 + tp * 1024 + 32);
        f32x4 p = {};
        p = __builtin_amdgcn_mfma_f32_16x16x32_bf16(h2f0, b0, p, 0, 0, 0);
        p = __builtin_amdgcn_mfma_f32_16x16x32_bf16(h2f1, b1, p, 0, 0, 0);
        float bias = w2l2b[etile * 16 + m];
#pragma unroll
        for (int r = 0; r < 4; ++r) {
            float w2v = fabsf(p[r] + bias);
            float hv = bf2f(hid[s0 + quad * 4 + r][etile * 16 + m]);
            qp[r] += hv * w2v;
        }
    }
#pragma unroll
    for (int off = 1; off < 16; off <<= 1) {
#pragma unroll
        for (int r = 0; r < 4; ++r) qp[r] += __shfl_xor(qp[r], off, 64);
    }
    if (m == 0) {
#pragma unroll
        for (int r = 0; r < 4; ++r) qacc[s0 + quad * 4 + r][wave & 1] = qp[r];
    }
    __syncthreads();

    // ---- Phase D: b2 + final sum (LDS-only) ----
    if (t < TB) {
        int s = t;
        float q = qacc[s][0] + qacc[s][1] + b2l2b[0];
        float acc2 = 0.f;
#pragma unroll
        for (int kk = 0; kk < 8; ++kk) {
            bf16x8 hv = *reinterpret_cast<const bf16x8*>(&y[s][192 + kk * 8]);
#pragma unroll
            for (int j = 0; j < 8; ++j)
                acc2 += bf2f((u16)hv[j]) * b2w[kk * 8 + j];
        }
        out[sbase + s] = q + acc2;
    }
}

extern "C" void kernel_launch(void* const* d_in, const int* in_sizes, int n_in,
                              void* d_out, int out_size, void* d_ws, size_t ws_size,
                              hipStream_t stream)
{
    const float* qs    = (const float*)d_in[0];
    const float* st    = (const float*)d_in[1];
    const float* w1l1w = (const float*)d_in[2];
    const float* w1l1b = (const float*)d_in[3];
    const float* w1l2w = (const float*)d_in[4];
    const float* w1l2b = (const float*)d_in[5];
    const float* w2l1w = (const float*)d_in[6];
    const float* w2l1b = (const float*)d_in[7];
    const float* w2l2w = (const float*)d_in[8];
    const float* w2l2b = (const float*)d_in[9];
    const float* b1w   = (const float*)d_in[10];
    const float* b1b   = (const float*)d_in[11];
    const float* b2l1w = (const float*)d_in[12];
    const float* b2l1b = (const float*)d_in[13];
    const float* b2l2w = (const float*)d_in[14];
    const float* b2l2b = (const float*)d_in[15];

    u16* wsb = (u16*)d_ws;

    cvt_weights<<<(WS_TOTAL + 255) / 256, 256, 0, stream>>>(
        w1l1w, w2l1w, b1w, b2l1w, w1l2w, w2l2w, wsb);

    int B = in_sizes[0] / NAG;        // 32768
    int grid = B / TB;                // 1024
    qmix_kernel<<<grid, 256, 0, stream>>>(
        qs, st, wsb,
        w1l1b, w1l2b, w2l1b, w2l2b, b1b, b2l1b, b2l2w, b2l2b,
        (float*)d_out);
}

// Round 7
// 152.121 us; speedup vs baseline: 1.7674x; 1.0275x over previous
//
#include <hip/hip_runtime.h>

typedef unsigned short u16;
typedef unsigned int u32;
typedef short bf16x8 __attribute__((ext_vector_type(8)));
typedef float f32x4 __attribute__((ext_vector_type(4)));
typedef u16 u16x4 __attribute__((ext_vector_type(4)));

#define NAG 32
#define STATE 512
#define EMBED 64
#define TB 64   // samples per block; grid = 512 = 2 blocks/CU, one round

// d_ws bf16 layout (u16 element offsets).
// [0, 131072)      : WA  = concat(w1l1w, w2l1w, b1w, b2l1w) as [256][512]
// [131072, 262144) : WB  = w1l2w [2048][64]
// [262144, 266240) : WC  = w2l2w [64][64]
#define OFF_W1L1 0
#define OFF_W2L1 32768
#define OFF_B1W  65536
#define OFF_B2L1 98304
#define OFF_W1L2 131072
#define OFF_W2L2 262144
#define WS_TOTAL 266240

__device__ __forceinline__ float bf2f(u16 u) {
    u32 i = ((u32)u) << 16; float f;
    __builtin_memcpy(&f, &i, 4); return f;
}
__device__ __forceinline__ u16 f2bf(float f) {
    u32 i; __builtin_memcpy(&i, &f, 4);
    return (u16)((i + 0x8000u) >> 16);
}
__device__ __forceinline__ bf16x8 ld8(const u16* p) {
    return *reinterpret_cast<const bf16x8*>(p);
}
__device__ __forceinline__ bf16x8 cvt8(f32x4 a, f32x4 b) {
    bf16x8 r;
#pragma unroll
    for (int i = 0; i < 4; ++i) r[i]     = (short)f2bf(a[i]);
#pragma unroll
    for (int i = 0; i < 4; ++i) r[i + 4] = (short)f2bf(b[i]);
    return r;
}
// async global->LDS DMA, 16B per lane (dest = wave-uniform base + lane*16)
__device__ __forceinline__ void dma16(const void* g, void* l) {
    __builtin_amdgcn_global_load_lds(
        (const __attribute__((address_space(1))) u32*)g,
        (__attribute__((address_space(3))) u32*)l, 16, 0, 0);
}

__global__ __launch_bounds__(256) void cvt_weights(
    const float* __restrict__ w1l1w, const float* __restrict__ w2l1w,
    const float* __restrict__ b1w,   const float* __restrict__ b2l1w,
    const float* __restrict__ w1l2w, const float* __restrict__ w2l2w,
    u16* __restrict__ ws)
{
    int idx = blockIdx.x * 256 + threadIdx.x;
    const float* src; int off;
    if      (idx < OFF_W2L1)  { src = w1l1w; off = OFF_W1L1; }
    else if (idx < OFF_B1W)   { src = w2l1w; off = OFF_W2L1; }
    else if (idx < OFF_B2L1)  { src = b1w;   off = OFF_B1W;  }
    else if (idx < OFF_W1L2)  { src = b2l1w; off = OFF_B2L1; }
    else if (idx < OFF_W2L2)  { src = w1l2w; off = OFF_W1L2; }
    else if (idx < WS_TOTAL)  { src = w2l2w; off = OFF_W2L2; }
    else return;
    ws[idx] = f2bf(src[idx - off]);
}

__global__ __launch_bounds__(256, 2) void qmix_kernel(
    const float* __restrict__ qs,    const float* __restrict__ st,
    const u16*  __restrict__ wsb,
    const float* __restrict__ w1l1b, const float* __restrict__ w1l2b,
    const float* __restrict__ w2l1b, const float* __restrict__ w2l2b,
    const float* __restrict__ b1b,   const float* __restrict__ b2l1b,
    const float* __restrict__ b2l2w, const float* __restrict__ b2l2b,
    float* __restrict__ out)
{
    __shared__ u16  wbuf[256 * 64];   // 32 KB weight slice (chunk-XOR swizzled); hid overlays later
    __shared__ u16  y[TB][264];       // 33 KB: [0:64) h1, [64:128) h2, [128:192) b1v, [192:256) hb
    __shared__ u16  qslb[TB][40];     // 5 KB agent_qs bf16 (row 80B, 16B-aligned)
    __shared__ u16  w1bs[2048];       // 4 KB w1l2b bf16
    __shared__ float qacc[TB];
    __shared__ float b2wv[64];
    // total ~76 KB -> 2 blocks/CU

    const int t    = threadIdx.x;
    const int wave = t >> 6, lane = t & 63;
    const int m = lane & 15, quad = lane >> 4;
    const int sbase = blockIdx.x * TB;
    const int s0 = wave * 16;          // this wave owns samples s0..s0+15 in ALL phases

    // ---- prologue staging: qs->bf16, w1l2b->bf16, b2w ----
    if (t < 64) b2wv[t] = b2l2w[t];
    {
        f32x4 q0 = *reinterpret_cast<const f32x4*>(qs + (size_t)sbase * NAG + t * 8);
        f32x4 q1 = *reinterpret_cast<const f32x4*>(qs + (size_t)sbase * NAG + t * 8 + 4);
        *reinterpret_cast<bf16x8*>(&qslb[t >> 2][(t & 3) * 8]) = cvt8(q0, q1);
        f32x4 w0 = *reinterpret_cast<const f32x4*>(w1l2b + t * 8);
        f32x4 w1 = *reinterpret_cast<const f32x4*>(w1l2b + t * 8 + 4);
        *reinterpret_cast<bf16x8*>(&w1bs[t * 8]) = cvt8(w0, w1);
    }

    // ---- Phase A biases (compile-time group selection, no runtime-indexed ptrs) ----
    float abias[16];
#pragma unroll
    for (int tt = 0; tt < 4; ++tt) abias[tt]      = w1l1b[tt * 16 + m];
#pragma unroll
    for (int tt = 0; tt < 4; ++tt) abias[tt + 4]  = w2l1b[tt * 16 + m];
#pragma unroll
    for (int tt = 0; tt < 4; ++tt) abias[tt + 8]  = b1b[tt * 16 + m];
#pragma unroll
    for (int tt = 0; tt < 4; ++tt) abias[tt + 12] = b2l1b[tt * 16 + m];

    // ---- Phase A: Y[64][256] = states @ WA^T; wave = 16 samples x 256 feats ----
    const float* astB = st + (size_t)(sbase + s0 + m) * STATE + quad * 8;
    const int rsub = lane >> 3, cch = lane & 7;

    f32x4 acc[16] = {};
    for (int ksl = 0; ksl < 8; ++ksl) {
        __syncthreads();   // previous slice fully consumed (also covers prologue LDS)
        // DMA WA k-slice [256 rows][64 u16]; wave stages rows wave*64..+63
#pragma unroll
        for (int j = 0; j < 8; ++j) {
            const int row = wave * 64 + j * 8 + rsub;
            const int sc  = cch ^ (row & 7);
            dma16(wsb + (size_t)row * STATE + ksl * 64 + sc * 8,
                  &wbuf[(wave * 64 + j * 8) * 64 + lane * 8]);
        }
        // A-fragments direct to VGPR (overlap the same drain)
        f32x4 av0 = *reinterpret_cast<const f32x4*>(astB + ksl * 64);
        f32x4 av1 = *reinterpret_cast<const f32x4*>(astB + ksl * 64 + 4);
        f32x4 av2 = *reinterpret_cast<const f32x4*>(astB + ksl * 64 + 32);
        f32x4 av3 = *reinterpret_cast<const f32x4*>(astB + ksl * 64 + 36);
        __builtin_amdgcn_s_waitcnt(0);
        __syncthreads();
        bf16x8 af0 = cvt8(av0, av1);
        bf16x8 af1 = cvt8(av2, av3);
#pragma unroll
        for (int tt = 0; tt < 16; ++tt) {
            const int brow = tt * 16 + m;
            bf16x8 b0 = ld8(&wbuf[brow * 64 + ((quad) ^ (brow & 7)) * 8]);
            acc[tt] = __builtin_amdgcn_mfma_f32_16x16x32_bf16(af0, b0, acc[tt], 0, 0, 0);
        }
#pragma unroll
        for (int tt = 0; tt < 16; ++tt) {
            const int brow = tt * 16 + m;
            bf16x8 b1 = ld8(&wbuf[brow * 64 + ((4 + quad) ^ (brow & 7)) * 8]);
            acc[tt] = __builtin_amdgcn_mfma_f32_16x16x32_bf16(af1, b1, acc[tt], 0, 0, 0);
        }
    }
#pragma unroll
    for (int tt = 0; tt < 16; ++tt) {
        const bool isrelu = (tt < 8) || (tt >= 12);   // tiles 8..11 = b1v (linear)
        const int fcol = tt * 16 + m;
#pragma unroll
        for (int r = 0; r < 4; ++r) {
            float v = acc[tt][r] + abias[tt];
            if (isrelu) v = fmaxf(v, 0.f);
            y[s0 + quad * 4 + r][fcol] = f2bf(v);
        }
    }
    __syncthreads();

    // ---- Phase B: hidden = elu(sum_a qs[s,a]*|h1 @ W1l2[a]^T + b| + b1v) ----
    bf16x8 haf0 = *reinterpret_cast<const bf16x8*>(&y[s0 + m][quad * 8]);
    bf16x8 haf1 = *reinterpret_cast<const bf16x8*>(&y[s0 + m][32 + quad * 8]);

    f32x4 hacc[4] = {};
    for (int bs = 0; bs < 8; ++bs) {
        __syncthreads();   // previous slice consumed
#pragma unroll
        for (int j = 0; j < 8; ++j) {
            const int row = wave * 64 + j * 8 + rsub;   // local row in 256-row slice
            const int sc  = cch ^ (row & 7);
            dma16(wsb + OFF_W1L2 + ((size_t)bs * 256 + row) * EMBED + sc * 8,
                  &wbuf[(wave * 64 + j * 8) * 64 + lane * 8]);
        }
        // qs for this slice's 4 agents (vector LDS read per sample-row)
        u16x4 qv4[4];
#pragma unroll
        for (int r = 0; r < 4; ++r)
            qv4[r] = *reinterpret_cast<const u16x4*>(&qslb[s0 + quad * 4 + r][bs * 4]);
        __builtin_amdgcn_s_waitcnt(0);
        __syncthreads();
#pragma unroll
        for (int aloc = 0; aloc < 4; ++aloc) {
#pragma unroll
            for (int tp = 0; tp < 4; ++tp) {
                const int row = aloc * 64 + tp * 16 + m;
                bf16x8 b0 = ld8(&wbuf[row * 64 + ((quad) ^ (row & 7)) * 8]);
                bf16x8 b1 = ld8(&wbuf[row * 64 + ((4 + quad) ^ (row & 7)) * 8]);
                f32x4 p = {};
                p = __builtin_amdgcn_mfma_f32_16x16x32_bf16(haf0, b0, p, 0, 0, 0);
                p = __builtin_amdgcn_mfma_f32_16x16x32_bf16(haf1, b1, p, 0, 0, 0);
                const float bias = bf2f(w1bs[(bs * 4 + aloc) * EMBED + tp * 16 + m]);
#pragma unroll
                for (int r = 0; r < 4; ++r)
                    hacc[tp][r] += bf2f((u16)qv4[r][aloc]) * fabsf(p[r] + bias);
            }
        }
    }
    __syncthreads();   // all waves done with wbuf -> safe to overlay hid
    u16* hid = wbuf;   // [64][66]
#pragma unroll
    for (int tp = 0; tp < 4; ++tp) {
#pragma unroll
        for (int r = 0; r < 4; ++r) {
            const int s = s0 + quad * 4 + r, e = tp * 16 + m;
            float v = hacc[tp][r] + bf2f(y[s][128 + e]);
            v = (v > 0.f) ? v : (__expf(v) - 1.f);
            hid[s * 66 + e] = f2bf(v);
        }
    }
    __syncthreads();

    // ---- Phase C: w2 = |h2 @ W2l2^T + b|; q = sum_e hidden*w2 (wave-local) ----
    bf16x8 h2f0 = *reinterpret_cast<const bf16x8*>(&y[s0 + m][64 + quad * 8]);
    bf16x8 h2f1 = *reinterpret_cast<const bf16x8*>(&y[s0 + m][96 + quad * 8]);

    f32x4 qp = {};
#pragma unroll
    for (int tp = 0; tp < 4; ++tp) {
        const u16* wc = wsb + OFF_W2L2 + (size_t)(tp * 16 + m) * EMBED + quad * 8;
        bf16x8 b0 = ld8(wc);
        bf16x8 b1 = ld8(wc + 32);
        f32x4 p = {};
        p = __builtin_amdgcn_mfma_f32_16x16x32_bf16(h2f0, b0, p, 0, 0, 0);
        p = __builtin_amdgcn_mfma_f32_16x16x32_bf16(h2f1, b1, p, 0, 0, 0);
        const float bias = w2l2b[tp * 16 + m];
#pragma unroll
        for (int r = 0; r < 4; ++r)
            qp[r] += bf2f(hid[(s0 + quad * 4 + r) * 66 + tp * 16 + m]) * fabsf(p[r] + bias);
    }
#pragma unroll
    for (int off = 1; off < 16; off <<= 1) {
#pragma unroll
        for (int r = 0; r < 4; ++r) qp[r] += __shfl_xor(qp[r], off, 64);
    }
    if (m == 0) {
#pragma unroll
        for (int r = 0; r < 4; ++r) qacc[s0 + quad * 4 + r] = qp[r];
    }
    __syncthreads();

    // ---- Phase D: b2 + final sum (LDS-only) ----
    if (t < TB) {
        float q = qacc[t] + b2l2b[0];
        float acc2 = 0.f;
#pragma unroll
        for (int kk = 0; kk < 8; ++kk) {
            bf16x8 hv = *reinterpret_cast<const bf16x8*>(&y[t][192 + kk * 8]);
#pragma unroll
            for (int j = 0; j < 8; ++j)
                acc2 += bf2f((u16)hv[j]) * b2wv[kk * 8 + j];
        }
        out[sbase + t] = q + acc2;
    }
}

extern "C" void kernel_launch(void* const* d_in, const int* in_sizes, int n_in,
                              void* d_out, int out_size, void* d_ws, size_t ws_size,
                              hipStream_t stream)
{
    const float* qs    = (const float*)d_in[0];
    const float* st    = (const float*)d_in[1];
    const float* w1l1w = (const float*)d_in[2];
    const float* w1l1b = (const float*)d_in[3];
    const float* w1l2w = (const float*)d_in[4];
    const float* w1l2b = (const float*)d_in[5];
    const float* w2l1w = (const float*)d_in[6];
    const float* w2l1b = (const float*)d_in[7];
    const float* w2l2w = (const float*)d_in[8];
    const float* w2l2b = (const float*)d_in[9];
    const float* b1w   = (const float*)d_in[10];
    const float* b1b   = (const float*)d_in[11];
    const float* b2l1w = (const float*)d_in[12];
    const float* b2l1b = (const float*)d_in[13];
    const float* b2l2w = (const float*)d_in[14];
    const float* b2l2b = (const float*)d_in[15];

    u16* wsb = (u16*)d_ws;

    cvt_weights<<<(WS_TOTAL + 255) / 256, 256, 0, stream>>>(
        w1l1w, w2l1w, b1w, b2l1w, w1l2w, w2l2w, wsb);

    int B = in_sizes[0] / NAG;        // 32768
    int grid = B / TB;                // 512 = 2 blocks/CU, single round
    qmix_kernel<<<grid, 256, 0, stream>>>(
        qs, st, wsb,
        w1l1b, w1l2b, w2l1b, w2l2b, b1b, b2l1b, b2l2w, b2l2b,
        (float*)d_out);
}